// Round 10
// baseline (285.471 us; speedup 1.0000x reference)
//
#include <hip/hip_runtime.h>
#include <cstdint>

#define NEGF (-1e18f)
#define GK 2048   // GEMM K
#define GN 1024   // GEMM N

typedef __attribute__((ext_vector_type(8))) short short8;     // 8 bf16 (4 VGPRs) MFMA A/B frag
typedef __attribute__((ext_vector_type(4))) float f32x4;      // MFMA C/D frag
typedef __attribute__((ext_vector_type(4))) unsigned short us4;
typedef __attribute__((ext_vector_type(8))) unsigned short us8;

__device__ __forceinline__ unsigned short f2bf(float f) {
    unsigned int u = __float_as_uint(f);
    u += 0x7FFFu + ((u >> 16) & 1u);          // RNE
    return (unsigned short)(u >> 16);
}
__device__ __forceinline__ float bf2f(unsigned short h) {
    return __uint_as_float(((unsigned int)h) << 16);
}
__device__ __forceinline__ float gelu_erf(float x) {
    return 0.5f * x * (1.0f + erff(x * 0.70710678118654752f));
}
// tanh-form GELU: max |diff| vs erf-GELU < 1e-3 (small vs 2.1e-2 threshold)
__device__ __forceinline__ float gelu_fast(float x) {
    const float y = 1.5957691216057308f * (x + 0.044715f * x * x * x);
    const float t = 1.0f - 2.0f / (__expf(y) + 1.0f);
    return 0.5f * x * (1.0f + t);
}
__device__ __forceinline__ void async_copy16(const void* g, void* l) {
    __builtin_amdgcn_global_load_lds(
        (const __attribute__((address_space(1))) unsigned int*)g,
        (__attribute__((address_space(3))) unsigned int*)l,
        16, 0, 0);
}

// ---------------- 1. weight transpose + bf16 convert (both weights in one dispatch)
__global__ __launch_bounds__(256) void wtrans2_kernel(const float* __restrict__ wmot,
                                                      const float* __restrict__ wapp,
                                                      unsigned short* __restrict__ wmotT,
                                                      unsigned short* __restrict__ wappT) {
    const int which = blockIdx.x >> 10;
    const float* w = which ? wapp : wmot;
    unsigned short* wT = which ? wappT : wmotT;
    const int idx = (blockIdx.x & 1023) * 256 + threadIdx.x;
    const int n = idx & 1023;
    const int k0 = (idx >> 10) << 3;
    us8 o;
    #pragma unroll
    for (int j = 0; j < 8; ++j) o[j] = f2bf(w[(size_t)(k0 + j) * 1024 + n]);
    *(us8*)(wT + (size_t)n * 2048 + k0) = o;
}

// ---------------- 2. fused: motion score + window softmax + app/vid bf16 convert
__global__ __launch_bounds__(256) void prep2_kernel(const float* __restrict__ clip_ft,
                                                    const int* __restrict__ lens,
                                                    const float* __restrict__ w_mot_wei,
                                                    const float* __restrict__ bsc,
                                                    unsigned short* __restrict__ app,   // [B][256][2048]
                                                    unsigned short* __restrict__ vid) { // [B][256][2048]
    __shared__ float sm2[2][4];
    const int b = blockIdx.x >> 3;
    const int c = blockIdx.x & 7;
    const int t = threadIdx.x;
    const int lane = t & 63, wv = t >> 6;
    const int d0 = t * 8;
    const int l0 = c * 32;
    const int len = lens[b];
    const float bias = bsc[0];
    const float* base = clip_ft + ((size_t)b * 256) * 2048 + d0;
    float wm[8];
    {
        f32x4 u = *(const f32x4*)(w_mot_wei + d0);
        f32x4 v = *(const f32x4*)(w_mot_wei + d0 + 4);
        #pragma unroll
        for (int j = 0; j < 4; ++j) { wm[j] = u[j]; wm[4 + j] = v[j]; }
    }
    float x0[8], x1[8], cur[8];
    float sc0 = NEGF, sc1 = NEGF, sc2 = NEGF;
    for (int i = 0; i < 34; ++i) {
        const int l = l0 + i;
        if (l < 256) {
            const f32x4* p = (const f32x4*)(base + (size_t)l * 2048);
            f32x4 u = p[0], v = p[1];
            #pragma unroll
            for (int j = 0; j < 4; ++j) { cur[j] = u[j]; cur[4 + j] = v[j]; }
            if (i < 32) {
                us8 o;
                #pragma unroll
                for (int j = 0; j < 8; ++j) o[j] = f2bf(cur[j]);
                *(us8*)(app + ((size_t)b * 256 + l) * 2048 + d0) = o;
            }
            float p8 = cur[0]*wm[0] + cur[1]*wm[1] + cur[2]*wm[2] + cur[3]*wm[3]
                     + cur[4]*wm[4] + cur[5]*wm[5] + cur[6]*wm[6] + cur[7]*wm[7];
            #pragma unroll
            for (int off = 32; off; off >>= 1) p8 += __shfl_xor(p8, off);
            if (lane == 0) sm2[i & 1][wv] = p8;
        }
        __syncthreads();                           // uniform; publishes sm2[i&1]
        if (l < 256) {
            float s = (sm2[i & 1][0] + sm2[i & 1][1]) + (sm2[i & 1][2] + sm2[i & 1][3]) + bias;
            sc2 = (l >= len) ? NEGF : s;
        }
        if (i >= 2) {
            const int lw = l - 2;
            if (lw < 254) {
                const float mx = fmaxf(sc0, fmaxf(sc1, sc2));
                const float e0 = expf(sc0 - mx), e1 = expf(sc1 - mx), e2 = expf(sc2 - mx);
                const float inv = 1.0f / (e0 + e1 + e2);
                const float a0 = e0 * inv, a1 = e1 * inv, a2 = e2 * inv;
                us8 o;
                #pragma unroll
                for (int j = 0; j < 8; ++j) o[j] = f2bf(a0 * x0[j] + a1 * x1[j] + a2 * cur[j]);
                *(us8*)(vid + ((size_t)b * 256 + lw) * 2048 + d0) = o;
            } else if (lw < 256) {
                us8 z = {};                         // zero pad rows 254,255
                *(us8*)(vid + ((size_t)b * 256 + lw) * 2048 + d0) = z;
            }
        }
        #pragma unroll
        for (int j = 0; j < 8; ++j) { x0[j] = x1[j]; x1[j] = cur[j]; }
        sc0 = sc1; sc1 = sc2;
    }
}

// ---------------- 3. fused dual bf16 MFMA GEMM — 256x256 tile, BK=64, 8 waves (2Mx4N),
// 8-phase schedule, m201-faithful skeleton: per phase {ds_read subtile | one stage-half |
// s_barrier | lgkmcnt(0) | setprio 16 MFMA}; counted vmcnt(6) ONLY at phases 4 & 8.
// R10: NO sched_barrier pinning — compiler free to interleave ds_read<->MFMA with its own
// fine-grained lgkmcnt (m97 strength; m141 showed pinning costs ~40%). asm "memory"
// clobbers still order all memory ops; barriers fence code motion; reg-only MFMA hoisting
// is safe (compiler auto-waits before consuming MFMAs).
__global__ __launch_bounds__(512, 2) void gemm8p_kernel(
        const unsigned short* __restrict__ Avid, const unsigned short* __restrict__ Aapp,
        const unsigned short* __restrict__ Bmot, const unsigned short* __restrict__ Bapp,
        const float* __restrict__ bmot, const float* __restrict__ bapp,
        const float* __restrict__ w_pool,
        unsigned short* __restrict__ Cmot, unsigned short* __restrict__ Capp,
        float* __restrict__ pspart) {             // [2][16384][16] strip partials
    __shared__ __align__(16) unsigned short lds_[65536];      // 128 KB: 2 bufs x (A 32KB | B 32KB)
    const int bid = blockIdx.x;
    const int virt = (bid & 7) * 64 + (bid >> 3);             // XCD-bijective (512 % 8 == 0)
    const int which = virt >> 8;
    const int rem = virt & 255;
    const int mtile = rem >> 2, ntile = rem & 3;  // ntile fastest: XCD keeps B (4MB) L2-resident
    const unsigned short* A  = which ? Aapp : Avid;
    const unsigned short* Bt = which ? Bapp : Bmot;
    const float* bias        = which ? bapp : bmot;
    unsigned short* C        = which ? Capp : Cmot;
    const int row0 = mtile * 256, col0 = ntile * 256;
    const int t = threadIdx.x, lane = t & 63, wave = t >> 6;
    const int wm = wave >> 2, wn = wave & 3;      // 2M x 4N waves, 128x64 output each
    const int lr = lane & 15, lk = lane >> 4;

    // ---- staging maps (pre-swizzled source: involution slot ^= row&7, rule 21)
    const int rr = t >> 3;                        // 0..63 row-within-call
    const int ss = (t & 7) ^ (rr & 7);            // source 16B k-slot
    const unsigned short* gA00 = A + (size_t)(row0 + rr)       * GK + ss * 8;  // A1 call0
    const unsigned short* gA01 = A + (size_t)(row0 + rr + 64)  * GK + ss * 8;  // A2 call0
    const unsigned short* gA10 = A + (size_t)(row0 + rr + 128) * GK + ss * 8;  // A1 call1
    const unsigned short* gA11 = A + (size_t)(row0 + rr + 192) * GK + ss * 8;  // A2 call1
    const int bcol = (rr & 31) + (rr >> 5) * 64;
    const unsigned short* gB00 = Bt + (size_t)(col0 + bcol)       * GK + ss * 8; // B1 call0
    const unsigned short* gB01 = Bt + (size_t)(col0 + bcol + 32)  * GK + ss * 8; // B2 call0
    const unsigned short* gB10 = Bt + (size_t)(col0 + bcol + 128) * GK + ss * 8; // B1 call1
    const unsigned short* gB11 = Bt + (size_t)(col0 + bcol + 160) * GK + ss * 8; // B2 call1

    // one stage-half = 16 KB = 2 async calls; LDS dest wave-uniform base + lane*16
    auto stA = [&](int h, int bsel, int tt) {
        const int dst = bsel * 32768 + h * 8192 + (wave << 9);
        async_copy16((h ? gA01 : gA00) + (size_t)tt * 64, lds_ + dst);
        async_copy16((h ? gA11 : gA10) + (size_t)tt * 64, lds_ + dst + 4096);
    };
    auto stB = [&](int nq, int bsel, int tt) {
        const int dst = bsel * 32768 + 16384 + nq * 8192 + (wave << 9);
        async_copy16((nq ? gB01 : gB00) + (size_t)tt * 64, lds_ + dst);
        async_copy16((nq ? gB11 : gB10) + (size_t)tt * 64, lds_ + dst + 4096);
    };
    // frag reads (swizzled): A quad qh -> region qh, call wm; B nq -> region nq, call wn>>1
    auto rdA = [&](short8* d, int bsel, int qh) {
        #pragma unroll
        for (int m = 0; m < 4; ++m) {
            const int r = m * 16 + lr;
            #pragma unroll
            for (int ks = 0; ks < 2; ++ks)
                d[m * 2 + ks] = *(const short8*)(lds_ + bsel * 32768 + qh * 8192 + wm * 4096
                                                 + r * 64 + (((ks * 4 + lk) ^ (r & 7)) << 3));
        }
    };
    auto rdB = [&](short8* d, int bsel, int nq) {
        #pragma unroll
        for (int n = 0; n < 2; ++n) {
            const int cc = (wn & 1) * 32 + n * 16 + lr;
            #pragma unroll
            for (int ks = 0; ks < 2; ++ks)
                d[n * 2 + ks] = *(const short8*)(lds_ + bsel * 32768 + 16384 + nq * 8192
                                                 + (wn >> 1) * 4096 + cc * 64
                                                 + (((ks * 4 + lk) ^ (cc & 7)) << 3));
        }
    };

    f32x4 acc[8][4] = {};
    short8 aF[8], bL[4], bH[4];

    auto mm = [&](int mr, int nc, short8* af, short8* bf) {
        #pragma unroll
        for (int m = 0; m < 4; ++m)
            #pragma unroll
            for (int n = 0; n < 2; ++n)
                #pragma unroll
                for (int ks = 0; ks < 2; ++ks)
                    acc[mr + m][nc + n] = __builtin_amdgcn_mfma_f32_16x16x32_bf16(
                        af[m * 2 + ks], bf[n * 2 + ks], acc[mr + m][nc + n], 0, 0, 0);
    };

#define OPEN  do { __builtin_amdgcn_s_barrier(); \
                   asm volatile("s_waitcnt lgkmcnt(0)" ::: "memory"); \
                   __builtin_amdgcn_s_setprio(1); } while (0)
#define CLOSE do { __builtin_amdgcn_s_setprio(0); \
                   __builtin_amdgcn_s_barrier(); } while (0)
#define CLOSEVM(N) do { __builtin_amdgcn_s_setprio(0); \
                   asm volatile("s_waitcnt vmcnt(" #N ")" ::: "memory"); \
                   __builtin_amdgcn_s_barrier(); } while (0)

    // prologue: tile0 complete + tile1 {A1,B1,B2}; vmcnt(6) -> tile0 landed
    stA(0, 0, 0); stB(0, 0, 0); stB(1, 0, 0); stA(1, 0, 0);
    stA(0, 1, 1); stB(0, 1, 1); stB(1, 1, 1);
    asm volatile("s_waitcnt vmcnt(6)" ::: "memory");
    __builtin_amdgcn_s_barrier();

    #pragma unroll 1
    for (int k = 0; k < 15; ++k) {                // iterations over tile pairs (2k, 2k+1)
        rdA(aF, 0, 0); rdB(bL, 0, 0); stA(1, 1, 2 * k + 1);
        OPEN; mm(0, 0, aF, bL); CLOSE;            // ph1: Q00 of tile 2k
        rdB(bH, 0, 1); stA(0, 0, 2 * k + 2);
        OPEN; mm(0, 2, aF, bH); CLOSE;            // ph2: Q01
        rdA(aF, 0, 1); stB(0, 0, 2 * k + 2);
        OPEN; mm(4, 0, aF, bL); CLOSE;            // ph3: Q10
        stB(1, 0, 2 * k + 2);
        OPEN; mm(4, 2, aF, bH); CLOSEVM(6);       // ph4: Q11 + counted wait
        rdA(aF, 1, 0); rdB(bL, 1, 0); stA(1, 0, 2 * k + 2);
        OPEN; mm(0, 0, aF, bL); CLOSE;            // ph5: Q00 of tile 2k+1
        rdB(bH, 1, 1); stA(0, 1, 2 * k + 3);
        OPEN; mm(0, 2, aF, bH); CLOSE;            // ph6
        rdA(aF, 1, 1); stB(0, 1, 2 * k + 3);
        OPEN; mm(4, 0, aF, bL); CLOSE;            // ph7
        stB(1, 1, 2 * k + 3);
        OPEN; mm(4, 2, aF, bH); CLOSEVM(6);       // ph8
    }
    // final iteration (tiles 30, 31): only deferred stage A2(31); drain at ph4
    rdA(aF, 0, 0); rdB(bL, 0, 0); stA(1, 1, 31);
    OPEN; mm(0, 0, aF, bL); CLOSE;
    rdB(bH, 0, 1);
    OPEN; mm(0, 2, aF, bH); CLOSE;
    rdA(aF, 0, 1);
    OPEN; mm(4, 0, aF, bL); CLOSE;
    OPEN; mm(4, 2, aF, bH); CLOSEVM(0);
    rdA(aF, 1, 0); rdB(bL, 1, 0);
    OPEN; mm(0, 0, aF, bL); CLOSE;
    rdB(bH, 1, 1);
    OPEN; mm(0, 2, aF, bH); CLOSE;
    rdA(aF, 1, 1);
    OPEN; mm(4, 0, aF, bL); CLOSE;
    OPEN; mm(4, 2, aF, bH); __builtin_amdgcn_s_setprio(0);
#undef OPEN
#undef CLOSE
#undef CLOSEVM

    // epilogue: C/D layout col=lane&15, row=(lane>>4)*4+i (HW-verified m89/m91)
    float wp[4], bz[4];
    #pragma unroll
    for (int n = 0; n < 4; ++n) {
        const int col = col0 + wn * 64 + n * 16 + lr;
        wp[n] = w_pool[col];
        bz[n] = bias[col];
    }
    const int strip = ntile * 4 + wn;
    #pragma unroll
    for (int m = 0; m < 8; ++m) {
        #pragma unroll
        for (int i = 0; i < 4; ++i) {
            const int row = row0 + wm * 128 + m * 16 + lk * 4 + i;
            float pr = 0.f;
            #pragma unroll
            for (int n = 0; n < 4; ++n) {
                const int col = col0 + wn * 64 + n * 16 + lr;
                const float g = gelu_fast(acc[m][n][i] + bz[n]);
                pr += g * wp[n];
                C[(size_t)row * GN + col] = f2bf(g);
            }
            #pragma unroll
            for (int off = 8; off; off >>= 1) pr += __shfl_xor(pr, off);  // reduce over lr group
            if (lr == 0) pspart[((size_t)which * 16384 + row) * 16 + strip] = pr;
        }
    }
}

// ---------------- 4. masked softmax + weighted sum; block = (b, which); thread owns 4 cols
__global__ __launch_bounds__(256) void pool2_kernel(const unsigned short* __restrict__ motion,
                                                    const unsigned short* __restrict__ appearance,
                                                    const float* __restrict__ pspart,
                                                    const int* __restrict__ lens,
                                                    const float* __restrict__ b_pool,
                                                    float* __restrict__ out) {
    __shared__ float sm[256];
    __shared__ float red[8];
    const int which = blockIdx.x & 1;
    const int b = blockIdx.x >> 1;
    const unsigned short* mat = (which ? appearance : motion) + (size_t)b * 256 * 1024;
    const int Lm = which ? 256 : 254;
    const int valid = which ? lens[b] : lens[b] - 2;
    const int t = threadIdx.x, lane = t & 63, wv = t >> 6;
    float v = NEGF;
    if (t < valid) {
        const float* pp = pspart + ((size_t)which * 16384 + b * 256 + t) * 16;
        float s = 0.f;
        #pragma unroll
        for (int j = 0; j < 16; ++j) s += pp[j];
        v = gelu_erf(s + b_pool[0]);
    }
    float mx = v;
    #pragma unroll
    for (int off = 32; off; off >>= 1) mx = fmaxf(mx, __shfl_xor(mx, off));
    if (lane == 0) red[wv] = mx;
    __syncthreads();
    mx = fmaxf(fmaxf(red[0], red[1]), fmaxf(red[2], red[3]));
    const float e = expf(v - mx);                 // masked rows -> exactly 0
    float s = e;
    #pragma unroll
    for (int off = 32; off; off >>= 1) s += __shfl_xor(s, off);
    if (lane == 0) red[4 + wv] = s;
    __syncthreads();
    s = red[4] + red[5] + red[6] + red[7];
    sm[t] = e / s;
    __syncthreads();
    const int col0 = t * 4;
    float a0 = 0.f, a1 = 0.f, a2 = 0.f, a3 = 0.f;
    for (int l = 0; l < Lm; ++l) {
        const float al = sm[l];                   // uniform scalar -> cheap branch
        if (al > 0.f) {
            us4 hv = *(const us4*)(mat + (size_t)l * 1024 + col0);
            a0 += al * bf2f(hv[0]);
            a1 += al * bf2f(hv[1]);
            a2 += al * bf2f(hv[2]);
            a3 += al * bf2f(hv[3]);
        }
    }
    float* o = out + (size_t)b * 2048 + which * 1024 + col0;
    o[0] = a0; o[1] = a1; o[2] = a2; o[3] = a3;
}

extern "C" void kernel_launch(void* const* d_in, const int* in_sizes, int n_in,
                              void* d_out, int out_size, void* d_ws, size_t ws_size,
                              hipStream_t stream) {
    const float* clip_ft   = (const float*)d_in[0];
    const int*   clip_lens = (const int*)d_in[1];
    const float* w_mot_wei = (const float*)d_in[2];
    const float* b_mot_wei = (const float*)d_in[3];
    const float* w_mot_fc  = (const float*)d_in[4];
    const float* b_mot_fc  = (const float*)d_in[5];
    const float* w_app_fc  = (const float*)d_in[6];
    const float* b_app_fc  = (const float*)d_in[7];
    const float* w_pool    = (const float*)d_in[8];
    const float* b_pool    = (const float*)d_in[9];
    float* out = (float*)d_out;

    char* ws = (char*)d_ws;
    size_t off = 0;
    auto carve = [&](size_t bytes) { void* p = ws + off; off += (bytes + 255) & ~(size_t)255; return p; };
    float*          pspart = (float*)carve((size_t)2 * 16384 * 16 * 4);
    unsigned short* wmotT  = (unsigned short*)carve((size_t)1024 * 2048 * 2);
    unsigned short* wappT  = (unsigned short*)carve((size_t)1024 * 2048 * 2);
    unsigned short* appb   = (unsigned short*)carve((size_t)64 * 256 * 2048 * 2);
    unsigned short* vidb   = (unsigned short*)carve((size_t)64 * 256 * 2048 * 2);  // padded rows
    unsigned short* motion = (unsigned short*)carve((size_t)64 * 256 * 1024 * 2);  // padded rows
    unsigned short* appear = (unsigned short*)carve((size_t)64 * 256 * 1024 * 2);
    (void)ws_size; (void)in_sizes; (void)n_in; (void)out_size;

    wtrans2_kernel<<<2048, 256, 0, stream>>>(w_mot_fc, w_app_fc, wmotT, wappT);
    prep2_kernel<<<512, 256, 0, stream>>>(clip_ft, clip_lens, w_mot_wei, b_mot_wei, appb, vidb);
    gemm8p_kernel<<<512, 512, 0, stream>>>(vidb, appb, wmotT, wappT,
                                           b_mot_fc, b_app_fc, w_pool, motion, appear, pspart);
    pool2_kernel<<<128, 256, 0, stream>>>(motion, appear, pspart, clip_lens, b_pool, out);
}

// Round 11
// 284.702 us; speedup vs baseline: 1.0027x; 1.0027x over previous
//
#include <hip/hip_runtime.h>
#include <cstdint>

#define NEGF (-1e18f)
#define GK 2048   // GEMM K
#define GN 1024   // GEMM N

typedef __attribute__((ext_vector_type(8))) short short8;     // 8 bf16 (4 VGPRs) MFMA A/B frag
typedef __attribute__((ext_vector_type(4))) float f32x4;      // MFMA C/D frag
typedef __attribute__((ext_vector_type(4))) unsigned short us4;
typedef __attribute__((ext_vector_type(8))) unsigned short us8;

__device__ __forceinline__ unsigned short f2bf(float f) {
    unsigned int u = __float_as_uint(f);
    u += 0x7FFFu + ((u >> 16) & 1u);          // RNE
    return (unsigned short)(u >> 16);
}
__device__ __forceinline__ float bf2f(unsigned short h) {
    return __uint_as_float(((unsigned int)h) << 16);
}
__device__ __forceinline__ float gelu_erf(float x) {
    return 0.5f * x * (1.0f + erff(x * 0.70710678118654752f));
}
// tanh-form GELU: max |diff| vs erf-GELU < 1e-3 (small vs 2.1e-2 threshold)
__device__ __forceinline__ float gelu_fast(float x) {
    const float y = 1.5957691216057308f * (x + 0.044715f * x * x * x);
    const float t = 1.0f - 2.0f / (__expf(y) + 1.0f);
    return 0.5f * x * (1.0f + t);
}
__device__ __forceinline__ void async_copy16(const void* g, void* l) {
    __builtin_amdgcn_global_load_lds(
        (const __attribute__((address_space(1))) unsigned int*)g,
        (__attribute__((address_space(3))) unsigned int*)l,
        16, 0, 0);
}

// ---------------- 1. weight transpose + bf16 convert (both weights in one dispatch)
__global__ __launch_bounds__(256) void wtrans2_kernel(const float* __restrict__ wmot,
                                                      const float* __restrict__ wapp,
                                                      unsigned short* __restrict__ wmotT,
                                                      unsigned short* __restrict__ wappT) {
    const int which = blockIdx.x >> 10;
    const float* w = which ? wapp : wmot;
    unsigned short* wT = which ? wappT : wmotT;
    const int idx = (blockIdx.x & 1023) * 256 + threadIdx.x;
    const int n = idx & 1023;
    const int k0 = (idx >> 10) << 3;
    us8 o;
    #pragma unroll
    for (int j = 0; j < 8; ++j) o[j] = f2bf(w[(size_t)(k0 + j) * 1024 + n]);
    *(us8*)(wT + (size_t)n * 2048 + k0) = o;
}

// ---------------- 2. fused: motion score + window softmax + app/vid bf16 convert
__global__ __launch_bounds__(256) void prep2_kernel(const float* __restrict__ clip_ft,
                                                    const int* __restrict__ lens,
                                                    const float* __restrict__ w_mot_wei,
                                                    const float* __restrict__ bsc,
                                                    unsigned short* __restrict__ app,   // [B][256][2048]
                                                    unsigned short* __restrict__ vid) { // [B][256][2048]
    __shared__ float sm2[2][4];
    const int b = blockIdx.x >> 3;
    const int c = blockIdx.x & 7;
    const int t = threadIdx.x;
    const int lane = t & 63, wv = t >> 6;
    const int d0 = t * 8;
    const int l0 = c * 32;
    const int len = lens[b];
    const float bias = bsc[0];
    const float* base = clip_ft + ((size_t)b * 256) * 2048 + d0;
    float wm[8];
    {
        f32x4 u = *(const f32x4*)(w_mot_wei + d0);
        f32x4 v = *(const f32x4*)(w_mot_wei + d0 + 4);
        #pragma unroll
        for (int j = 0; j < 4; ++j) { wm[j] = u[j]; wm[4 + j] = v[j]; }
    }
    float x0[8], x1[8], cur[8];
    float sc0 = NEGF, sc1 = NEGF, sc2 = NEGF;
    for (int i = 0; i < 34; ++i) {
        const int l = l0 + i;
        if (l < 256) {
            const f32x4* p = (const f32x4*)(base + (size_t)l * 2048);
            f32x4 u = p[0], v = p[1];
            #pragma unroll
            for (int j = 0; j < 4; ++j) { cur[j] = u[j]; cur[4 + j] = v[j]; }
            if (i < 32) {
                us8 o;
                #pragma unroll
                for (int j = 0; j < 8; ++j) o[j] = f2bf(cur[j]);
                *(us8*)(app + ((size_t)b * 256 + l) * 2048 + d0) = o;
            }
            float p8 = cur[0]*wm[0] + cur[1]*wm[1] + cur[2]*wm[2] + cur[3]*wm[3]
                     + cur[4]*wm[4] + cur[5]*wm[5] + cur[6]*wm[6] + cur[7]*wm[7];
            #pragma unroll
            for (int off = 32; off; off >>= 1) p8 += __shfl_xor(p8, off);
            if (lane == 0) sm2[i & 1][wv] = p8;
        }
        __syncthreads();                           // uniform; publishes sm2[i&1]
        if (l < 256) {
            float s = (sm2[i & 1][0] + sm2[i & 1][1]) + (sm2[i & 1][2] + sm2[i & 1][3]) + bias;
            sc2 = (l >= len) ? NEGF : s;
        }
        if (i >= 2) {
            const int lw = l - 2;
            if (lw < 254) {
                const float mx = fmaxf(sc0, fmaxf(sc1, sc2));
                const float e0 = expf(sc0 - mx), e1 = expf(sc1 - mx), e2 = expf(sc2 - mx);
                const float inv = 1.0f / (e0 + e1 + e2);
                const float a0 = e0 * inv, a1 = e1 * inv, a2 = e2 * inv;
                us8 o;
                #pragma unroll
                for (int j = 0; j < 8; ++j) o[j] = f2bf(a0 * x0[j] + a1 * x1[j] + a2 * cur[j]);
                *(us8*)(vid + ((size_t)b * 256 + lw) * 2048 + d0) = o;
            } else if (lw < 256) {
                us8 z = {};                         // zero pad rows 254,255
                *(us8*)(vid + ((size_t)b * 256 + lw) * 2048 + d0) = z;
            }
        }
        #pragma unroll
        for (int j = 0; j < 8; ++j) { x0[j] = x1[j]; x1[j] = cur[j]; }
        sc0 = sc1; sc1 = sc2;
    }
}

// ---------------- 3. fused dual bf16 MFMA GEMM — 256x256 tile, BK=64, 8 waves (2Mx4N),
// 8-phase schedule; R11: NO explicit lgkmcnt(0) in OPEN — our ds_reads are compiler-visible
// typed loads, so hipcc emits precise per-use lgkmcnt(N) before each consuming MFMA,
// overlapping early MFMAs with the tail of the phase's LDS reads (m97 strength).
// Safety: every ds_read is consumed by this phase's MFMAs (issue precedes CLOSE barrier),
// so buffer-overwrite protection (barrier + counted vmcnt, "memory"-clobbered) is intact.
__global__ __launch_bounds__(512, 2) void gemm8p_kernel(
        const unsigned short* __restrict__ Avid, const unsigned short* __restrict__ Aapp,
        const unsigned short* __restrict__ Bmot, const unsigned short* __restrict__ Bapp,
        const float* __restrict__ bmot, const float* __restrict__ bapp,
        const float* __restrict__ w_pool,
        unsigned short* __restrict__ Cmot, unsigned short* __restrict__ Capp,
        float* __restrict__ pspart) {             // [2][16384][16] strip partials
    __shared__ __align__(16) unsigned short lds_[65536];      // 128 KB: 2 bufs x (A 32KB | B 32KB)
    const int bid = blockIdx.x;
    const int virt = (bid & 7) * 64 + (bid >> 3);             // XCD-bijective (512 % 8 == 0)
    const int which = virt >> 8;
    const int rem = virt & 255;
    const int mtile = rem >> 2, ntile = rem & 3;  // ntile fastest: XCD keeps B (4MB) L2-resident
    const unsigned short* A  = which ? Aapp : Avid;
    const unsigned short* Bt = which ? Bapp : Bmot;
    const float* bias        = which ? bapp : bmot;
    unsigned short* C        = which ? Capp : Cmot;
    const int row0 = mtile * 256, col0 = ntile * 256;
    const int t = threadIdx.x, lane = t & 63, wave = t >> 6;
    const int wm = wave >> 2, wn = wave & 3;      // 2M x 4N waves, 128x64 output each
    const int lr = lane & 15, lk = lane >> 4;

    // ---- staging maps (pre-swizzled source: involution slot ^= row&7, rule 21)
    const int rr = t >> 3;                        // 0..63 row-within-call
    const int ss = (t & 7) ^ (rr & 7);            // source 16B k-slot
    const unsigned short* gA00 = A + (size_t)(row0 + rr)       * GK + ss * 8;  // A1 call0
    const unsigned short* gA01 = A + (size_t)(row0 + rr + 64)  * GK + ss * 8;  // A2 call0
    const unsigned short* gA10 = A + (size_t)(row0 + rr + 128) * GK + ss * 8;  // A1 call1
    const unsigned short* gA11 = A + (size_t)(row0 + rr + 192) * GK + ss * 8;  // A2 call1
    const int bcol = (rr & 31) + (rr >> 5) * 64;
    const unsigned short* gB00 = Bt + (size_t)(col0 + bcol)       * GK + ss * 8; // B1 call0
    const unsigned short* gB01 = Bt + (size_t)(col0 + bcol + 32)  * GK + ss * 8; // B2 call0
    const unsigned short* gB10 = Bt + (size_t)(col0 + bcol + 128) * GK + ss * 8; // B1 call1
    const unsigned short* gB11 = Bt + (size_t)(col0 + bcol + 160) * GK + ss * 8; // B2 call1

    // one stage-half = 16 KB = 2 async calls; LDS dest wave-uniform base + lane*16
    auto stA = [&](int h, int bsel, int tt) {
        const int dst = bsel * 32768 + h * 8192 + (wave << 9);
        async_copy16((h ? gA01 : gA00) + (size_t)tt * 64, lds_ + dst);
        async_copy16((h ? gA11 : gA10) + (size_t)tt * 64, lds_ + dst + 4096);
    };
    auto stB = [&](int nq, int bsel, int tt) {
        const int dst = bsel * 32768 + 16384 + nq * 8192 + (wave << 9);
        async_copy16((nq ? gB01 : gB00) + (size_t)tt * 64, lds_ + dst);
        async_copy16((nq ? gB11 : gB10) + (size_t)tt * 64, lds_ + dst + 4096);
    };
    // frag reads (swizzled): A quad qh -> region qh, call wm; B nq -> region nq, call wn>>1
    auto rdA = [&](short8* d, int bsel, int qh) {
        #pragma unroll
        for (int m = 0; m < 4; ++m) {
            const int r = m * 16 + lr;
            #pragma unroll
            for (int ks = 0; ks < 2; ++ks)
                d[m * 2 + ks] = *(const short8*)(lds_ + bsel * 32768 + qh * 8192 + wm * 4096
                                                 + r * 64 + (((ks * 4 + lk) ^ (r & 7)) << 3));
        }
    };
    auto rdB = [&](short8* d, int bsel, int nq) {
        #pragma unroll
        for (int n = 0; n < 2; ++n) {
            const int cc = (wn & 1) * 32 + n * 16 + lr;
            #pragma unroll
            for (int ks = 0; ks < 2; ++ks)
                d[n * 2 + ks] = *(const short8*)(lds_ + bsel * 32768 + 16384 + nq * 8192
                                                 + (wn >> 1) * 4096 + cc * 64
                                                 + (((ks * 4 + lk) ^ (cc & 7)) << 3));
        }
    };

    f32x4 acc[8][4] = {};
    short8 aF[8], bL[4], bH[4];

    auto mm = [&](int mr, int nc, short8* af, short8* bf) {
        #pragma unroll
        for (int m = 0; m < 4; ++m)
            #pragma unroll
            for (int n = 0; n < 2; ++n)
                #pragma unroll
                for (int ks = 0; ks < 2; ++ks)
                    acc[mr + m][nc + n] = __builtin_amdgcn_mfma_f32_16x16x32_bf16(
                        af[m * 2 + ks], bf[n * 2 + ks], acc[mr + m][nc + n], 0, 0, 0);
    };

#define OPEN  do { __builtin_amdgcn_s_barrier(); \
                   __builtin_amdgcn_s_setprio(1); } while (0)
#define CLOSE do { __builtin_amdgcn_s_setprio(0); \
                   __builtin_amdgcn_s_barrier(); } while (0)
#define CLOSEVM(N) do { __builtin_amdgcn_s_setprio(0); \
                   asm volatile("s_waitcnt vmcnt(" #N ")" ::: "memory"); \
                   __builtin_amdgcn_s_barrier(); } while (0)

    // prologue: tile0 complete + tile1 {A1,B1,B2}; vmcnt(6) -> tile0 landed
    stA(0, 0, 0); stB(0, 0, 0); stB(1, 0, 0); stA(1, 0, 0);
    stA(0, 1, 1); stB(0, 1, 1); stB(1, 1, 1);
    asm volatile("s_waitcnt vmcnt(6)" ::: "memory");
    __builtin_amdgcn_s_barrier();

    #pragma unroll 1
    for (int k = 0; k < 15; ++k) {                // iterations over tile pairs (2k, 2k+1)
        rdA(aF, 0, 0); rdB(bL, 0, 0); stA(1, 1, 2 * k + 1);
        OPEN; mm(0, 0, aF, bL); CLOSE;            // ph1: Q00 of tile 2k
        rdB(bH, 0, 1); stA(0, 0, 2 * k + 2);
        OPEN; mm(0, 2, aF, bH); CLOSE;            // ph2: Q01
        rdA(aF, 0, 1); stB(0, 0, 2 * k + 2);
        OPEN; mm(4, 0, aF, bL); CLOSE;            // ph3: Q10
        stB(1, 0, 2 * k + 2);
        OPEN; mm(4, 2, aF, bH); CLOSEVM(6);       // ph4: Q11 + counted wait
        rdA(aF, 1, 0); rdB(bL, 1, 0); stA(1, 0, 2 * k + 2);
        OPEN; mm(0, 0, aF, bL); CLOSE;            // ph5: Q00 of tile 2k+1
        rdB(bH, 1, 1); stA(0, 1, 2 * k + 3);
        OPEN; mm(0, 2, aF, bH); CLOSE;            // ph6
        rdA(aF, 1, 1); stB(0, 1, 2 * k + 3);
        OPEN; mm(4, 0, aF, bL); CLOSE;            // ph7
        stB(1, 1, 2 * k + 3);
        OPEN; mm(4, 2, aF, bH); CLOSEVM(6);       // ph8
    }
    // final iteration (tiles 30, 31): only deferred stage A2(31); drain at ph4
    rdA(aF, 0, 0); rdB(bL, 0, 0); stA(1, 1, 31);
    OPEN; mm(0, 0, aF, bL); CLOSE;
    rdB(bH, 0, 1);
    OPEN; mm(0, 2, aF, bH); CLOSE;
    rdA(aF, 0, 1);
    OPEN; mm(4, 0, aF, bL); CLOSE;
    OPEN; mm(4, 2, aF, bH); CLOSEVM(0);
    rdA(aF, 1, 0); rdB(bL, 1, 0);
    OPEN; mm(0, 0, aF, bL); CLOSE;
    rdB(bH, 1, 1);
    OPEN; mm(0, 2, aF, bH); CLOSE;
    rdA(aF, 1, 1);
    OPEN; mm(4, 0, aF, bL); CLOSE;
    OPEN; mm(4, 2, aF, bH); __builtin_amdgcn_s_setprio(0);
#undef OPEN
#undef CLOSE
#undef CLOSEVM

    // epilogue: C/D layout col=lane&15, row=(lane>>4)*4+i (HW-verified m89/m91)
    float wp[4], bz[4];
    #pragma unroll
    for (int n = 0; n < 4; ++n) {
        const int col = col0 + wn * 64 + n * 16 + lr;
        wp[n] = w_pool[col];
        bz[n] = bias[col];
    }
    const int strip = ntile * 4 + wn;
    #pragma unroll
    for (int m = 0; m < 8; ++m) {
        #pragma unroll
        for (int i = 0; i < 4; ++i) {
            const int row = row0 + wm * 128 + m * 16 + lk * 4 + i;
            float pr = 0.f;
            #pragma unroll
            for (int n = 0; n < 4; ++n) {
                const int col = col0 + wn * 64 + n * 16 + lr;
                const float g = gelu_fast(acc[m][n][i] + bz[n]);
                pr += g * wp[n];
                C[(size_t)row * GN + col] = f2bf(g);
            }
            #pragma unroll
            for (int off = 8; off; off >>= 1) pr += __shfl_xor(pr, off);  // reduce over lr group
            if (lr == 0) pspart[((size_t)which * 16384 + row) * 16 + strip] = pr;
        }
    }
}

// ---------------- 4. masked softmax + weighted sum; block = (b, which); thread owns 4 cols
__global__ __launch_bounds__(256) void pool2_kernel(const unsigned short* __restrict__ motion,
                                                    const unsigned short* __restrict__ appearance,
                                                    const float* __restrict__ pspart,
                                                    const int* __restrict__ lens,
                                                    const float* __restrict__ b_pool,
                                                    float* __restrict__ out) {
    __shared__ float sm[256];
    __shared__ float red[8];
    const int which = blockIdx.x & 1;
    const int b = blockIdx.x >> 1;
    const unsigned short* mat = (which ? appearance : motion) + (size_t)b * 256 * 1024;
    const int Lm = which ? 256 : 254;
    const int valid = which ? lens[b] : lens[b] - 2;
    const int t = threadIdx.x, lane = t & 63, wv = t >> 6;
    float v = NEGF;
    if (t < valid) {
        const float* pp = pspart + ((size_t)which * 16384 + b * 256 + t) * 16;
        float s = 0.f;
        #pragma unroll
        for (int j = 0; j < 16; ++j) s += pp[j];
        v = gelu_erf(s + b_pool[0]);
    }
    float mx = v;
    #pragma unroll
    for (int off = 32; off; off >>= 1) mx = fmaxf(mx, __shfl_xor(mx, off));
    if (lane == 0) red[wv] = mx;
    __syncthreads();
    mx = fmaxf(fmaxf(red[0], red[1]), fmaxf(red[2], red[3]));
    const float e = expf(v - mx);                 // masked rows -> exactly 0
    float s = e;
    #pragma unroll
    for (int off = 32; off; off >>= 1) s += __shfl_xor(s, off);
    if (lane == 0) red[4 + wv] = s;
    __syncthreads();
    s = red[4] + red[5] + red[6] + red[7];
    sm[t] = e / s;
    __syncthreads();
    const int col0 = t * 4;
    float a0 = 0.f, a1 = 0.f, a2 = 0.f, a3 = 0.f;
    for (int l = 0; l < Lm; ++l) {
        const float al = sm[l];                   // uniform scalar -> cheap branch
        if (al > 0.f) {
            us4 hv = *(const us4*)(mat + (size_t)l * 1024 + col0);
            a0 += al * bf2f(hv[0]);
            a1 += al * bf2f(hv[1]);
            a2 += al * bf2f(hv[2]);
            a3 += al * bf2f(hv[3]);
        }
    }
    float* o = out + (size_t)b * 2048 + which * 1024 + col0;
    o[0] = a0; o[1] = a1; o[2] = a2; o[3] = a3;
}

extern "C" void kernel_launch(void* const* d_in, const int* in_sizes, int n_in,
                              void* d_out, int out_size, void* d_ws, size_t ws_size,
                              hipStream_t stream) {
    const float* clip_ft   = (const float*)d_in[0];
    const int*   clip_lens = (const int*)d_in[1];
    const float* w_mot_wei = (const float*)d_in[2];
    const float* b_mot_wei = (const float*)d_in[3];
    const float* w_mot_fc  = (const float*)d_in[4];
    const float* b_mot_fc  = (const float*)d_in[5];
    const float* w_app_fc  = (const float*)d_in[6];
    const float* b_app_fc  = (const float*)d_in[7];
    const float* w_pool    = (const float*)d_in[8];
    const float* b_pool    = (const float*)d_in[9];
    float* out = (float*)d_out;

    char* ws = (char*)d_ws;
    size_t off = 0;
    auto carve = [&](size_t bytes) { void* p = ws + off; off += (bytes + 255) & ~(size_t)255; return p; };
    float*          pspart = (float*)carve((size_t)2 * 16384 * 16 * 4);
    unsigned short* wmotT  = (unsigned short*)carve((size_t)1024 * 2048 * 2);
    unsigned short* wappT  = (unsigned short*)carve((size_t)1024 * 2048 * 2);
    unsigned short* appb   = (unsigned short*)carve((size_t)64 * 256 * 2048 * 2);
    unsigned short* vidb   = (unsigned short*)carve((size_t)64 * 256 * 2048 * 2);  // padded rows
    unsigned short* motion = (unsigned short*)carve((size_t)64 * 256 * 1024 * 2);  // padded rows
    unsigned short* appear = (unsigned short*)carve((size_t)64 * 256 * 1024 * 2);
    (void)ws_size; (void)in_sizes; (void)n_in; (void)out_size;

    wtrans2_kernel<<<2048, 256, 0, stream>>>(w_mot_fc, w_app_fc, wmotT, wappT);
    prep2_kernel<<<512, 256, 0, stream>>>(clip_ft, clip_lens, w_mot_wei, b_mot_wei, appb, vidb);
    gemm8p_kernel<<<512, 512, 0, stream>>>(vidb, appb, wmotT, wappT,
                                           b_mot_fc, b_app_fc, w_pool, motion, appear, pspart);
    pool2_kernel<<<128, 256, 0, stream>>>(motion, appear, pspart, clip_lens, b_pool, out);
}